// Round 22
// baseline (123.874 us; speedup 1.0000x reference)
//
#include <hip/hip_runtime.h>
#include <hip/hip_bf16.h>

#define C_  19
#define D_  512
#define H_  4
#define DH_ 128
#define NROW 65536
#define CHP_ 96

typedef float f32x4 __attribute__((ext_vector_type(4)));
typedef short bf16x8 __attribute__((ext_vector_type(8)));

__device__ __forceinline__ unsigned short f2bf(float f) {
  union { __hip_bfloat16 h; unsigned short s; } u;
  u.h = __float2bfloat16(f);
  return u.s;
}
__device__ __forceinline__ float bf2f(unsigned short h) {
  return __uint_as_float(((unsigned int)h) << 16);
}
__device__ __forceinline__ bf16x8 ld_cvt8(const float* p) {
  f32x4 v0 = *(const f32x4*)p;
  f32x4 v1 = *(const f32x4*)(p + 4);
  bf16x8 a;
  a[0]=(short)f2bf(v0[0]); a[1]=(short)f2bf(v0[1]);
  a[2]=(short)f2bf(v0[2]); a[3]=(short)f2bf(v0[3]);
  a[4]=(short)f2bf(v1[0]); a[5]=(short)f2bf(v1[1]);
  a[6]=(short)f2bf(v1[2]); a[7]=(short)f2bf(v1[3]);
  return a;
}
__device__ __forceinline__ float dot4(f32x4 a, f32x4 b, float acc) {
  return fmaf(a[0],b[0], fmaf(a[1],b[1], fmaf(a[2],b[2], fmaf(a[3],b[3], acc))));
}

// ---- prep (r21-verbatim): vectorized dots, frag-order layouts, bo at p=80 --
__global__ __launch_bounds__(512) void prep(
    const float* __restrict__ ce,
    const float* __restrict__ Wq, const float* __restrict__ bq,
    const float* __restrict__ Wk, const float* __restrict__ bk,
    const float* __restrict__ Wv, const float* __restrict__ bv,
    const float* __restrict__ Wo, const float* __restrict__ bo,
    unsigned short* __restrict__ Mtf, unsigned short* __restrict__ Utf,
    float* __restrict__ s0g)
{
  __shared__ __attribute__((aligned(16))) float KV[2][DH_];
  __shared__ float KVp[512];

  const int p = blockIdx.x;   // 0..95
  const int m = threadIdx.x;  // 0..511
  const int mt_off = (p>>4)*8192 + (m>>5)*512 + ((((m>>3)&3)<<4) + (p&15))*8 + (m&7);
  const int ut_off = ((m>>4)*3 + (p>>5))*512 + ((((p>>3)&3)<<4) + (m&15))*8 + (p&7);
  const int c = p >> 2, h = p & 3;

  if (c >= C_) {   // dead slots; p==80 carries bo (Wa col 80 is 1.0)
    if (p < 80) { Mtf[mt_off] = 0; if (m == 0) s0g[p] = 0.f; }
    Utf[ut_off] = (p == 80) ? f2bf(bo[m]) : (unsigned short)0;
    return;
  }

  {
    const int which = m >> 8;            // 0:K 1:V
    const int dh    = (m >> 1) & 127;
    const int half  = m & 1;
    const float* w = (which ? Wv : Wk) + (size_t)(h*DH_ + dh)*D_ + half*256;
    const float* e = ce + (size_t)c*D_ + half*256;
    float a0 = 0.f, a1 = 0.f, a2 = 0.f, a3 = 0.f;
    #pragma unroll
    for (int d = 0; d < 256; d += 16) {
      a0 = dot4(*(const f32x4*)(w+d   ), *(const f32x4*)(e+d   ), a0);
      a1 = dot4(*(const f32x4*)(w+d+4 ), *(const f32x4*)(e+d+4 ), a1);
      a2 = dot4(*(const f32x4*)(w+d+8 ), *(const f32x4*)(e+d+8 ), a2);
      a3 = dot4(*(const f32x4*)(w+d+12), *(const f32x4*)(e+d+12), a3);
    }
    KVp[m] = (a0 + a1) + (a2 + a3);
  }
  __syncthreads();
  if (m < 256) {
    const int which = m >> 7, dh = m & 127;
    KV[which][dh] = KVp[2*m] + KVp[2*m+1] + (which ? bv : bk)[h*DH_ + dh];
  }
  __syncthreads();

  const float rs128 = 0.08838834764831843f;  // 1/sqrt(128)

  {
    float m0 = 0.f, m1 = 0.f, m2 = 0.f, m3 = 0.f;
    const float* wq = Wq + (size_t)(h*DH_)*D_ + m;
    #pragma unroll 8
    for (int dh = 0; dh < DH_; dh += 4) {
      m0 = fmaf(wq[(size_t)(dh  )*D_], KV[0][dh  ], m0);
      m1 = fmaf(wq[(size_t)(dh+1)*D_], KV[0][dh+1], m1);
      m2 = fmaf(wq[(size_t)(dh+2)*D_], KV[0][dh+2], m2);
      m3 = fmaf(wq[(size_t)(dh+3)*D_], KV[0][dh+3], m3);
    }
    Mtf[mt_off] = f2bf(((m0 + m1) + (m2 + m3)) * rs128);
  }

  {
    const float* wor = Wo + (size_t)m*D_ + h*DH_;
    float u0 = 0.f, u1 = 0.f, u2 = 0.f, u3 = 0.f;
    #pragma unroll
    for (int dh = 0; dh < DH_; dh += 16) {
      u0 = dot4(*(const f32x4*)(wor+dh   ), *(const f32x4*)(&KV[1][dh   ]), u0);
      u1 = dot4(*(const f32x4*)(wor+dh+4 ), *(const f32x4*)(&KV[1][dh+4 ]), u1);
      u2 = dot4(*(const f32x4*)(wor+dh+8 ), *(const f32x4*)(&KV[1][dh+8 ]), u2);
      u3 = dot4(*(const f32x4*)(wor+dh+12), *(const f32x4*)(&KV[1][dh+12]), u3);
    }
    Utf[ut_off] = f2bf((u0 + u1) + (u2 + u3));
  }

  if (m == 0) {
    float sa = 0.f;
    for (int dh = 0; dh < DH_; ++dh) sa = fmaf(bq[h*DH_+dh], KV[0][dh], sa);
    s0g[p] = sa * rs128;
  }
}

// ---- fused64x8: 64 rows/block, 8 waves x 8 rows, 2 barriers, 16 waves/CU --
// Phase 1 MFMA M-dim half-wasted (rows 8..15 dup 0..7, r16-proven); VGPR
// capped 128 via launch_bounds -> 2 blocks/CU co-resident.
__global__ __launch_bounds__(512, 4) void fused64x8(
    const float* __restrict__ x,
    const unsigned short* __restrict__ Mtf,  // frag-ordered [5][16][64][8]
    const unsigned short* __restrict__ Utf,  // frag-ordered [32][3][64][8]
    const float* __restrict__ s0g,           // [80] permuted
    const float* __restrict__ gamma, const float* __restrict__ beta,
    float* __restrict__ out)
{
  __shared__ __attribute__((aligned(16))) unsigned short Xbf[64*512]; // 64KB swizzled
  __shared__ __attribute__((aligned(16))) unsigned short WaL[64][104];
  __shared__ float rs_[64][2], rq_[64][2];

  const int t    = threadIdx.x;
  const int wave = t >> 6;        // 0..7
  const int lane = t & 63;
  const int lhi  = lane >> 4;
  const int llo  = lane & 15;
  const int row0 = blockIdx.x * 64;
  const int wrow = wave * 8;      // this wave's local row base (8 rows)

  // ---- phase 0: stage this wave's 8 rows -> Xbf (bf16, swizzled) ----
  {
    #pragma unroll
    for (int j = 0; j < 8; ++j) {
      bf16x8 a = ld_cvt8(x + (size_t)(row0 + wrow + j)*D_ + lane*8);
      int byteoff = (wrow + j)*1024 + ((lane*16) ^ (j << 4));
      *(bf16x8*)((char*)Xbf + byteoff) = a;
    }
  }
  asm volatile("s_waitcnt lgkmcnt(0)" ::: "memory");
  __builtin_amdgcn_sched_barrier(0);

  // ---- phase 1: S-GEMM, ks-outer, 5 accs; A rows clamped to this wave's 8 --
  {
    const int arow = llo & 7;              // rows 8..15 duplicate 0..7
    const char* xb = (const char*)Xbf + (wrow + arow)*1024;
    const int swz = arow << 4;
    f32x4 acc0 = (f32x4){0,0,0,0}, acc1 = acc0, acc2 = acc0, acc3 = acc0, acc4 = acc0;
    #pragma unroll
    for (int ks = 0; ks < 16; ++ks) {
      bf16x8 a = *(const bf16x8*)(xb + ((ks*64 + lhi*16) ^ swz));
      acc0 = __builtin_amdgcn_mfma_f32_16x16x32_bf16(a, *(const bf16x8*)(Mtf + 0*8192 + ks*512 + lane*8), acc0, 0, 0, 0);
      acc1 = __builtin_amdgcn_mfma_f32_16x16x32_bf16(a, *(const bf16x8*)(Mtf + 1*8192 + ks*512 + lane*8), acc1, 0, 0, 0);
      acc2 = __builtin_amdgcn_mfma_f32_16x16x32_bf16(a, *(const bf16x8*)(Mtf + 2*8192 + ks*512 + lane*8), acc2, 0, 0, 0);
      acc3 = __builtin_amdgcn_mfma_f32_16x16x32_bf16(a, *(const bf16x8*)(Mtf + 3*8192 + ks*512 + lane*8), acc3, 0, 0, 0);
      acc4 = __builtin_amdgcn_mfma_f32_16x16x32_bf16(a, *(const bf16x8*)(Mtf + 4*8192 + ks*512 + lane*8), acc4, 0, 0, 0);
    }
    // in-register softmax over p (h = llo&3 lane-invariant under xor 4,8)
    const bool dead = (llo >= 12);   // slot p=64+llo: c = 16+(llo>>2) == 19
    float s0v0 = s0g[llo], s0v1 = s0g[16+llo], s0v2 = s0g[32+llo],
          s0v3 = s0g[48+llo], s0v4 = s0g[64+llo];
    #pragma unroll
    for (int r = 0; r < 4; ++r) {
      float v0 = acc0[r] + s0v0;
      float v1 = acc1[r] + s0v1;
      float v2 = acc2[r] + s0v2;
      float v3 = acc3[r] + s0v3;
      float v4 = dead ? -1e30f : (acc4[r] + s0v4);
      float mx = fmaxf(fmaxf(fmaxf(v0, v1), fmaxf(v2, v3)), v4);
      mx = fmaxf(mx, __shfl_xor(mx, 4, 64));
      mx = fmaxf(mx, __shfl_xor(mx, 8, 64));
      float e0 = __expf(v0 - mx), e1 = __expf(v1 - mx), e2 = __expf(v2 - mx),
            e3 = __expf(v3 - mx), e4 = dead ? 0.f : __expf(v4 - mx);
      float sm = e0 + e1 + e2 + e3 + e4;
      sm += __shfl_xor(sm, 4, 64);
      sm += __shfl_xor(sm, 8, 64);
      float inv = 1.f / sm;
      if (lhi < 2) {                       // real rows only (0..7 of this wave)
        int lr = wrow + lhi*4 + r;
        WaL[lr][     llo] = f2bf(e0 * inv);
        WaL[lr][16 + llo] = f2bf(e1 * inv);
        WaL[lr][32 + llo] = f2bf(e2 * inv);
        WaL[lr][48 + llo] = f2bf(e3 * inv);
        WaL[lr][64 + llo] = f2bf(e4 * inv);
      }
    }
    // pad cols 80..95 for this wave's 8 rows: col 80 = 1.0 (bo), rest 0
    if (lane < 32) {
      int prow = wrow + (lane & 7);
      int cj   = (lane >> 3) & 3;
      WaL[prow][80 + cj*4 + 0] = (cj == 0) ? (unsigned short)0x3F80 : (unsigned short)0;
      WaL[prow][80 + cj*4 + 1] = 0;
      WaL[prow][80 + cj*4 + 2] = 0;
      WaL[prow][80 + cj*4 + 3] = 0;
    }
  }
  __syncthreads();   // BAR1: WaL + all Xbf staging visible block-wide

  // ---- phase 3 (single pass): 8 waves cover 64 rows x 512 cols ----
  const int rg = wave >> 1;       // 0..3: 16-row group
  const int cs = wave & 1;        // 256-col half
  f32x4 oacc[16];
  #pragma unroll
  for (int i = 0; i < 16; ++i) oacc[i] = (f32x4){0.f,0.f,0.f,0.f};
  #pragma unroll
  for (int ks = 0; ks < 3; ++ks) {
    bf16x8 a = *(const bf16x8*)&WaL[rg*16 + llo][ks*32 + lhi*8];
    #pragma unroll
    for (int tile = 0; tile < 16; ++tile) {
      int ntile = cs*16 + tile;
      bf16x8 b = *(const bf16x8*)(Utf + (size_t)(ntile*3 + ks)*512 + lane*8);
      oacc[tile] = __builtin_amdgcn_mfma_f32_16x16x32_bf16(a, b, oacc[tile], 0, 0, 0);
    }
  }
  // oacc[tile][r] = (attn+bo)[local m = rg*16+lhi*4+r][n = cs*256+tile*16+llo]

  // ---- epilogue: +x residual (LDS bf16), LN stats, store ----
  float s[4] = {0,0,0,0}, q[4] = {0,0,0,0};
  #pragma unroll
  for (int tile = 0; tile < 16; ++tile) {
    int n = cs*256 + tile*16 + llo;
    #pragma unroll
    for (int r = 0; r < 4; ++r) {
      int m = rg*16 + lhi*4 + r;
      float xres = bf2f(*(const unsigned short*)
          ((const char*)Xbf + m*1024 + ((n*2) ^ ((m & 7) << 4))));
      float val = oacc[tile][r] + xres;
      oacc[tile][r] = val;
      s[r] += val;
      q[r] = fmaf(val, val, q[r]);
    }
  }
  #pragma unroll
  for (int r = 0; r < 4; ++r) {
    #pragma unroll
    for (int off = 1; off < 16; off <<= 1) {
      s[r] += __shfl_xor(s[r], off, 64);
      q[r] += __shfl_xor(q[r], off, 64);
    }
  }
  if (llo == 0) {
    #pragma unroll
    for (int r = 0; r < 4; ++r) {
      rs_[rg*16 + lhi*4 + r][cs] = s[r];
      rq_[rg*16 + lhi*4 + r][cs] = q[r];
    }
  }
  __syncthreads();   // BAR2: stats ready
  float mu_r[4], rstd_r[4];
  #pragma unroll
  for (int r = 0; r < 4; ++r) {
    int m = rg*16 + lhi*4 + r;
    float sum = rs_[m][0] + rs_[m][1];
    float sq  = rq_[m][0] + rq_[m][1];
    float mu  = sum * (1.f/(float)D_);
    float var = sq * (1.f/(float)D_) - mu*mu;
    mu_r[r]   = mu;
    rstd_r[r] = rsqrtf(var + 1e-5f);
  }
  #pragma unroll
  for (int tile = 0; tile < 16; ++tile) {
    int n = cs*256 + tile*16 + llo;
    float g = gamma[n], bt = beta[n];
    #pragma unroll
    for (int r = 0; r < 4; ++r) {
      int m = rg*16 + lhi*4 + r;
      out[(size_t)(row0 + m)*D_ + n] = (oacc[tile][r] - mu_r[r]) * rstd_r[r] * g + bt;
    }
  }
}

extern "C" void kernel_launch(void* const* d_in, const int* in_sizes, int n_in,
                              void* d_out, int out_size, void* d_ws, size_t ws_size,
                              hipStream_t stream) {
  const float* x     = (const float*)d_in[0];
  const float* ce    = (const float*)d_in[1];
  const float* Wq    = (const float*)d_in[2];
  const float* bq    = (const float*)d_in[3];
  const float* Wk    = (const float*)d_in[4];
  const float* bk    = (const float*)d_in[5];
  const float* Wv    = (const float*)d_in[6];
  const float* bv    = (const float*)d_in[7];
  const float* Wo    = (const float*)d_in[8];
  const float* bo    = (const float*)d_in[9];
  const float* gamma = (const float*)d_in[10];
  const float* beta  = (const float*)d_in[11];
  float* out = (float*)d_out;

  char* ws = (char*)d_ws;
  unsigned short* Mtf = (unsigned short*)(ws);           // 80*512*2 = 81920
  unsigned short* Utf = (unsigned short*)(ws + 81920);   // 512*96*2 = 98304
  float* s0g          = (float*)(ws + 180224);           // 320

  prep<<<CHP_, 512, 0, stream>>>(ce, Wq, bq, Wk, bk, Wv, bv, Wo, bo,
                                 Mtf, Utf, s0g);
  fused64x8<<<NROW/64, 512, 0, stream>>>(x, Mtf, Utf, s0g, gamma, beta, out);
}